// Round 7
// baseline (163.498 us; speedup 1.0000x reference)
//
#include <hip/hip_runtime.h>
#include <hip/hip_bf16.h>

#define VOCABN 50000
#define BN 128
#define CN 5
#define HN 50
#define LN 32
#define DN 300
#define DP 320     // padded K
#define KNN 20

typedef __bf16    bf16x8 __attribute__((ext_vector_type(8)));
typedef float     f32x4  __attribute__((ext_vector_type(4)));
typedef _Float16  f16x8  __attribute__((ext_vector_type(8)));

#if __has_builtin(__builtin_amdgcn_exp2f)
#define FEXP2 __builtin_amdgcn_exp2f
#else
#define FEXP2 exp2f
#endif
#if __has_builtin(__builtin_amdgcn_logf)
#define FLOG2 __builtin_amdgcn_logf
#else
#define FLOG2 log2f
#endif

#define LOG2E 1.4426950408889634f
#define LN2F  0.6931471805599453f

// async global->LDS DMA, 16B per lane; LDS dest must be wave-uniform base (m104)
__device__ __forceinline__ void gload_lds16(const void* g, void* l) {
    __builtin_amdgcn_global_load_lds(
        (const __attribute__((address_space(1))) void*)g,
        (__attribute__((address_space(3))) void*)l, 16, 0, 0);
}

// ---------------- kernel 1: normalize vocab -> bf16 table [VOCAB][DP] ----------------
__global__ __launch_bounds__(256) void knorm_embed(const float* __restrict__ emb,
                                                   __hip_bfloat162* __restrict__ tab2) {
    const int v = blockIdx.x;
    const float* row = emb + (size_t)v * DN;
    const int t = threadIdx.x;

    float x0 = (t < DN) ? row[t] : 0.f;
    float x1 = (t + 256 < DN) ? row[t + 256] : 0.f;
    float ss = x0 * x0 + x1 * x1;
    #pragma unroll
    for (int off = 32; off; off >>= 1) ss += __shfl_xor(ss, off);
    __shared__ float red[4];
    if ((t & 63) == 0) red[t >> 6] = ss;
    __syncthreads();
    float tot = red[0] + red[1] + red[2] + red[3];
    float scale = 1.0f / fmaxf(sqrtf(tot), 1e-8f);

    if (t < DP / 2) {
        int e = t * 2;
        float a = (e < DN) ? row[e] * scale : 0.f;
        float b = (e + 1 < DN) ? row[e + 1] * scale : 0.f;
        __hip_bfloat162 p;
        p.x = __float2bfloat16(a);
        p.y = __float2bfloat16(b);
        tab2[(size_t)v * (DP / 2) + t] = p;
    }
}

// ---------------- kernel 2a: GEMM -> sim (f16), 2-phase global_load_lds pipeline ----------------
// Slice layout: [160 rows][32 bf16] = 64B rows, linear (2-way bank alias = free, m136).
__global__ __launch_bounds__(320, 4) void knrm_gemm(const int* __restrict__ cand,
                                                    const int* __restrict__ clik,
                                                    const ushort* __restrict__ tab,
                                                    _Float16* __restrict__ simg) {
    __shared__ __align__(16) ushort   Abuf[2][160 * 32];  // 2 x 10 KB
    __shared__ __align__(16) ushort   Bbuf[2][160 * 32];  // 2 x 10 KB
    __shared__ __align__(16) _Float16 simbuf[160 * 32];   // 10 KB
    __shared__ int tokA[160];
    __shared__ int tokB[160];

    const int t    = threadIdx.x;
    const int lane = t & 63;
    const int w    = t >> 6;          // wave 0..4 == candidate c
    // T1: bijective XCD swizzle (grid 1280 = 8 x 160)
    const int bid  = (blockIdx.x & 7) * 160 + (blockIdx.x >> 3);
    const int b    = bid / 10;
    const int hc   = bid % 10;

    if (t < 160) tokA[t] = cand[b * (CN * LN) + t];
    else         tokB[t - 160] = clik[b * (HN * LN) + hc * 160 + (t - 160)];
    __syncthreads();

    const int m15 = lane & 15;
    const int g4  = lane >> 4;

    // per-thread gather bases (fixed rows/chunks; only ss*64 varies)
    const int cid0 = w * 64 + lane;           // chunk ids (16B units), 640 chunks/slice
    const int cid1 = 320 + w * 64 + lane;
    const char* sa0 = (const char*)tab + (size_t)tokA[cid0 >> 2] * (DP * 2) + (cid0 & 3) * 16;
    const char* sa1 = (const char*)tab + (size_t)tokA[cid1 >> 2] * (DP * 2) + (cid1 & 3) * 16;
    const char* sb0 = (const char*)tab + (size_t)tokB[cid0 >> 2] * (DP * 2) + (cid0 & 3) * 16;
    const char* sb1 = (const char*)tab + (size_t)tokB[cid1 >> 2] * (DP * 2) + (cid1 & 3) * 16;
    // wave-uniform LDS dest bases (lane*16 appended by HW)
    const int ldsoff0 = (w * 64) * 16;        // == cid0*16 - lane*16
    const int ldsoff1 = (320 + w * 64) * 16;

    f32x4 acc[2][10];
    #pragma unroll
    for (int at = 0; at < 2; ++at)
        #pragma unroll
        for (int jg = 0; jg < 10; ++jg)
            acc[at][jg] = (f32x4){0.f, 0.f, 0.f, 0.f};

    // prologue: stage slice 0
    gload_lds16(sa0, (char*)&Abuf[0][0] + ldsoff0);
    gload_lds16(sa1, (char*)&Abuf[0][0] + ldsoff1);
    gload_lds16(sb0, (char*)&Bbuf[0][0] + ldsoff0);
    gload_lds16(sb1, (char*)&Bbuf[0][0] + ldsoff1);
    __syncthreads();

    int cur = 0;
    for (int ss = 0; ss < 10; ++ss) {         // 10 K-steps of 32
        if (ss < 9) {                         // T3 2-phase: issue next-slice DMA before compute
            const int nxt = cur ^ 1;
            const size_t ko = (size_t)(ss + 1) * 64;
            gload_lds16(sa0 + ko, (char*)&Abuf[nxt][0] + ldsoff0);
            gload_lds16(sa1 + ko, (char*)&Abuf[nxt][0] + ldsoff1);
            gload_lds16(sb0 + ko, (char*)&Bbuf[nxt][0] + ldsoff0);
            gload_lds16(sb1 + ko, (char*)&Bbuf[nxt][0] + ldsoff1);
        }
        const char* A = (const char*)&Abuf[cur][0];
        const char* B = (const char*)&Bbuf[cur][0];
        bf16x8 af0 = *(const bf16x8*)(A + (w * 32 + m15) * 64 + g4 * 16);
        bf16x8 af1 = *(const bf16x8*)(A + (w * 32 + 16 + m15) * 64 + g4 * 16);
        #pragma unroll
        for (int jg = 0; jg < 10; ++jg) {
            bf16x8 bf = *(const bf16x8*)(B + (jg * 16 + m15) * 64 + g4 * 16);
            acc[0][jg] = __builtin_amdgcn_mfma_f32_16x16x32_bf16(af0, bf, acc[0][jg], 0, 0, 0);
            acc[1][jg] = __builtin_amdgcn_mfma_f32_16x16x32_bf16(af1, bf, acc[1][jg], 0, 0, 0);
        }
        __syncthreads();                      // drains DMA (vmcnt) + frees buf[cur]
        cur ^= 1;
    }

    // Coalesced epilogue (R6-proven): per hl, tiles -> simbuf (LDS), then linear int4 stores.
    const size_t simg_base = ((size_t)b * CN * HN + (size_t)hc * 5) * (LN * LN);
    #pragma unroll
    for (int hl = 0; hl < 5; ++hl) {
        // C/D layout col=lane&15, row=(lane>>4)*4+reg [m89-verified]
        #pragma unroll
        for (int at = 0; at < 2; ++at)
            #pragma unroll
            for (int jgl = 0; jgl < 2; ++jgl)
                #pragma unroll
                for (int r = 0; r < 4; ++r) {
                    int i = w * 32 + at * 16 + g4 * 4 + r;   // c*32 + row
                    int j = jgl * 16 + m15;
                    simbuf[i * 32 + j] = (_Float16)acc[at][2 * hl + jgl][r];
                }
        __syncthreads();
        #pragma unroll
        for (int it = 0; it < 2; ++it) {
            int q = it * 320 + t;
            int c = q >> 7, off = q & 127;
            int4 v = *(const int4*)((const char*)simbuf + q * 16);
            size_t byteoff = (simg_base + ((size_t)c * HN + hl) * (LN * LN)) * 2 + off * 16;
            *(int4*)((char*)simg + byteoff) = v;
        }
        __syncthreads();
    }
}

// ---------------- kernel 2b: streaming kernel-pooling, factorized Gaussians (R5-proven) ----------------
// exp(-50(s-mu_k)^2) = e0 * t^m * e^{-m^2/2},  e0=e^{-50 s^2}, t=e^{10 s}, m=10*mu_k in [-9,9]
__global__ __launch_bounds__(256, 8) void knrm_pool(const _Float16* __restrict__ sim,
                                                    const float* __restrict__ ltr_w,
                                                    float* __restrict__ score) {
    const int n    = blockIdx.x * 256 + threadIdx.x;   // 1,024,000 threads
    const int lane = n & 63;
    const int wv   = n >> 6;          // ((b*C + c)*25 + h2)
    const int bc   = wv / 25;
    const int h2   = wv % 25;
    const int h    = h2 * 2 + (lane >> 5);
    const int i    = lane & 31;

    const f16x8* rowv = (const f16x8*)(sim + ((size_t)(bc * HN + h) * LN + i) * LN);

    const float C1   = 10.0f * LOG2E;    // t  = 2^( C1*s)
    const float C2   = -50.0f * LOG2E;   // e0 = 2^( C2*s^2)
    const float AK19 = 849.3218002880191f;  // sqrt(LOG2E / (2*0.001^2))

    float Q[KNN];
    #pragma unroll
    for (int k = 0; k < KNN; ++k) Q[k] = 0.f;

    #pragma unroll
    for (int jc = 0; jc < 4; ++jc) {
        f16x8 v = rowv[jc];
        #pragma unroll
        for (int e = 0; e < 8; ++e) {
            float s  = (float)v[e];
            float cs = C1 * s;
            float t  = FEXP2(cs);
            float u  = FEXP2(-cs);
            float e0 = FEXP2(C2 * (s * s));
            Q[9] += e0;
            float ap = e0, am = e0;
            ap *= t;  Q[10] += ap;   am *= u;  Q[8] += am;
            ap *= t;  Q[11] += ap;   am *= u;  Q[7] += am;
            ap *= t;  Q[12] += ap;   am *= u;  Q[6] += am;
            ap *= t;  Q[13] += ap;   am *= u;  Q[5] += am;
            ap *= t;  Q[14] += ap;   am *= u;  Q[4] += am;
            ap *= t;  Q[15] += ap;   am *= u;  Q[3] += am;
            ap *= t;  Q[16] += ap;   am *= u;  Q[2] += am;
            ap *= t;  Q[17] += ap;   am *= u;  Q[1] += am;
            ap *= t;  Q[18] += ap;   am *= u;  Q[0] += am;
            float d = fmaf(s, AK19, -AK19);          // (s-1)*AK19
            Q[19] += FEXP2(-(d * d));                // sharp sigma=0.001 kernel
        }
    }

    // e^{-m^2/2} for |m|=0..9
    static const float CkT[10] = {
        1.0f, 0.6065306597126334f, 0.1353352832366127f, 0.011108996538242306f,
        3.3546262790251185e-4f, 3.7266531720786709e-6f, 1.5229979744712628e-8f,
        2.2897348456191135e-11f, 1.2664165549094176e-14f, 2.576757109154981e-18f };

    const float* wrow = ltr_w + h * KNN;
    float res = 0.f;
    #pragma unroll
    for (int k = 0; k < KNN - 1; ++k) {
        int a = (k < 9) ? (9 - k) : (k - 9);
        float p = fmaxf(Q[k] * CkT[a], 1e-10f);
        res += wrow[k] * FLOG2(p);
    }
    res += wrow[KNN - 1] * FLOG2(fmaxf(Q[KNN - 1], 1e-10f));
    res *= LN2F;

    #pragma unroll
    for (int off = 32; off; off >>= 1) res += __shfl_xor(res, off);
    if (lane == 0) atomicAdd(&score[bc], res);
}

// Slice buffers: [row][64 ushorts] = 128B rows; 16B chunks XOR-swizzled (fallback only).
__device__ inline bf16x8 ldfrag(const ushort* buf, int row, int chunk) {
    int pos = chunk ^ (row & 7);
    return *(const bf16x8*)((const char*)buf + row * 128 + pos * 16);
}

// ---------------- fallback fused kernel (R3-proven) for small ws ----------------
__global__ __launch_bounds__(320, 4) void knrm_fused(const int* __restrict__ cand,
                                                     const int* __restrict__ clik,
                                                     const ushort* __restrict__ tab,
                                                     const float* __restrict__ ltr_w,
                                                     float* __restrict__ score) {
    __shared__ __align__(16) ushort   Abuf[160 * 64];
    __shared__ __align__(16) ushort   Bbuf[160 * 64];
    __shared__ __align__(16) _Float16 simbuf[160 * 32];
    __shared__ int   tokA[160];
    __shared__ int   tokB[160];
    __shared__ float red[5][5];

    const int t    = threadIdx.x;
    const int lane = t & 63;
    const int w    = t >> 6;
    const int bid  = blockIdx.x;
    const int b    = bid / 10;
    const int hc   = bid % 10;

    if (t < 160) tokA[t] = cand[b * (CN * LN) + t];
    else         tokB[t - 160] = clik[b * (HN * LN) + hc * 160 + (t - 160)];
    __syncthreads();

    const int m15 = lane & 15;
    const int g4  = lane >> 4;

    f32x4 acc[2][10];
    #pragma unroll
    for (int at = 0; at < 2; ++at)
        #pragma unroll
        for (int jg = 0; jg < 10; ++jg)
            acc[at][jg] = (f32x4){0.f, 0.f, 0.f, 0.f};

    for (int ss = 0; ss < 5; ++ss) {
        __syncthreads();
        {
            int4 rg[4];
            #pragma unroll
            for (int it = 0; it < 4; ++it) {
                int cid = it * 320 + t, row = cid >> 3, c = cid & 7;
                rg[it] = *(const int4*)((const char*)tab +
                    (size_t)tokA[row] * (DP * 2) + ss * 128 + ((c ^ (row & 7)) << 4));
            }
            #pragma unroll
            for (int it = 0; it < 4; ++it) {
                int cid = it * 320 + t, row = cid >> 3, c = cid & 7;
                *(int4*)((char*)Abuf + row * 128 + c * 16) = rg[it];
            }
            #pragma unroll
            for (int it = 0; it < 4; ++it) {
                int cid = it * 320 + t, row = cid >> 3, c = cid & 7;
                rg[it] = *(const int4*)((const char*)tab +
                    (size_t)tokB[row] * (DP * 2) + ss * 128 + ((c ^ (row & 7)) << 4));
            }
            #pragma unroll
            for (int it = 0; it < 4; ++it) {
                int cid = it * 320 + t, row = cid >> 3, c = cid & 7;
                *(int4*)((char*)Bbuf + row * 128 + c * 16) = rg[it];
            }
        }
        __syncthreads();
        #pragma unroll
        for (int kc = 0; kc < 2; ++kc) {
            bf16x8 af0 = ldfrag(Abuf, w * 32 + m15,      kc * 4 + g4);
            bf16x8 af1 = ldfrag(Abuf, w * 32 + 16 + m15, kc * 4 + g4);
            #pragma unroll
            for (int jg = 0; jg < 10; ++jg) {
                bf16x8 bf = ldfrag(Bbuf, jg * 16 + m15, kc * 4 + g4);
                acc[0][jg] = __builtin_amdgcn_mfma_f32_16x16x32_bf16(af0, bf, acc[0][jg], 0, 0, 0);
                acc[1][jg] = __builtin_amdgcn_mfma_f32_16x16x32_bf16(af1, bf, acc[1][jg], 0, 0, 0);
            }
        }
    }

    const int kq = t % 20;
    const int r0 = t / 20;
    const float sig = (kq == 19) ? 0.001f : 0.1f;
    const float ak  = sqrtf(LOG2E / (2.0f * sig * sig));
    const float bk  = -(0.1f * (float)kq - 0.9f) * ak;

    float accs[5] = {0.f, 0.f, 0.f, 0.f, 0.f};

    #pragma unroll
    for (int h = 0; h < 5; ++h) {
        __syncthreads();
        #pragma unroll
        for (int at = 0; at < 2; ++at)
            #pragma unroll
            for (int jgl = 0; jgl < 2; ++jgl)
                #pragma unroll
                for (int r = 0; r < 4; ++r) {
                    int i = w * 32 + at * 16 + g4 * 4 + r;
                    int j = jgl * 16 + m15;
                    simbuf[i * 32 + j] = (_Float16)acc[at][2 * h + jgl][r];
                }
        __syncthreads();

        const float wl = ltr_w[(hc * 5 + h) * KNN + kq] * LN2F;
        #pragma unroll
        for (int it = 0; it < 10; ++it) {
            const f16x8* srow = (const f16x8*)&simbuf[(it * 16 + r0) * 32];
            float p0 = 0.f, p1 = 0.f, p2 = 0.f, p3 = 0.f;
            #pragma unroll
            for (int jc = 0; jc < 4; ++jc) {
                f16x8 v = srow[jc];
                float d0 = fmaf((float)v[0], ak, bk);
                float d1 = fmaf((float)v[1], ak, bk);
                float d2 = fmaf((float)v[2], ak, bk);
                float d3 = fmaf((float)v[3], ak, bk);
                float d4 = fmaf((float)v[4], ak, bk);
                float d5 = fmaf((float)v[5], ak, bk);
                float d6 = fmaf((float)v[6], ak, bk);
                float d7 = fmaf((float)v[7], ak, bk);
                p0 += FEXP2(-(d0 * d0));
                p1 += FEXP2(-(d1 * d1));
                p2 += FEXP2(-(d2 * d2));
                p3 += FEXP2(-(d3 * d3));
                p0 += FEXP2(-(d4 * d4));
                p1 += FEXP2(-(d5 * d5));
                p2 += FEXP2(-(d6 * d6));
                p3 += FEXP2(-(d7 * d7));
            }
            float pooled = fmaxf((p0 + p1) + (p2 + p3), 1e-10f);
            accs[it >> 1] += FLOG2(pooled) * wl;
        }
    }

    #pragma unroll
    for (int c = 0; c < 5; ++c) {
        float v = accs[c];
        #pragma unroll
        for (int off = 32; off; off >>= 1) v += __shfl_xor(v, off);
        accs[c] = v;
    }
    __syncthreads();
    if (lane == 0)
        #pragma unroll
        for (int c = 0; c < 5; ++c) red[w][c] = accs[c];
    __syncthreads();
    if (t < 5) {
        float s = red[0][t] + red[1][t] + red[2][t] + red[3][t] + red[4][t];
        atomicAdd(&score[b * CN + t], s);
    }
}

// ---------------- kernel 3: log_softmax over C (ltr_b cancels) ----------------
__global__ __launch_bounds__(128) void knrm_final(const float* __restrict__ score,
                                                  float* __restrict__ out) {
    int b = threadIdx.x;
    if (b < BN) {
        float s[CN];
        float m = -1e30f;
        #pragma unroll
        for (int c = 0; c < CN; ++c) { s[c] = score[b * CN + c]; m = fmaxf(m, s[c]); }
        float sum = 0.f;
        #pragma unroll
        for (int c = 0; c < CN; ++c) sum += FEXP2((s[c] - m) * LOG2E);
        float lse = m + FLOG2(sum) * LN2F;
        #pragma unroll
        for (int c = 0; c < CN; ++c) out[b * CN + c] = s[c] - lse;
    }
}

extern "C" void kernel_launch(void* const* d_in, const int* in_sizes, int n_in,
                              void* d_out, int out_size, void* d_ws, size_t ws_size,
                              hipStream_t stream) {
    const int*   cand  = (const int*)d_in[0];   // [B,C,L]
    const int*   clik  = (const int*)d_in[1];   // [B,H,L]
    const float* emb   = (const float*)d_in[2]; // [VOCAB,D]
    const float* ltr_w = (const float*)d_in[3]; // [1,H*KN]
    float* out = (float*)d_out;

    const size_t TAB_B = (size_t)VOCABN * DP * 2;                 // 32,000,000
    const size_t SIM_B = (size_t)BN * CN * HN * LN * LN * 2;      // 65,536,000

    __hip_bfloat162* tab2 = (__hip_bfloat162*)d_ws;
    ushort* tab = (ushort*)d_ws;

    knorm_embed<<<VOCABN, 256, 0, stream>>>(emb, tab2);

    if (ws_size >= TAB_B + SIM_B + BN * CN * sizeof(float)) {
        _Float16* simg = (_Float16*)((char*)d_ws + TAB_B);
        float* score   = (float*)((char*)d_ws + TAB_B + SIM_B);
        hipMemsetAsync(score, 0, BN * CN * sizeof(float), stream);
        knrm_gemm<<<BN * 10, 320, 0, stream>>>(cand, clik, tab, simg);
        knrm_pool<<<(BN * CN * HN * LN) / 256, 256, 0, stream>>>(simg, ltr_w, score);
        knrm_final<<<1, 128, 0, stream>>>(score, out);
    } else {
        float* score = (float*)((char*)d_ws + TAB_B);
        hipMemsetAsync(score, 0, BN * CN * sizeof(float), stream);
        knrm_fused<<<BN * 10, 320, 0, stream>>>(cand, clik, tab, ltr_w, score);
        knrm_final<<<1, 128, 0, stream>>>(score, out);
    }
}

// Round 8
// 158.994 us; speedup vs baseline: 1.0283x; 1.0283x over previous
//
#include <hip/hip_runtime.h>
#include <hip/hip_bf16.h>

#define VOCABN 50000
#define BN 128
#define CN 5
#define HN 50
#define LN 32
#define DN 300
#define DP 320     // padded K
#define KNN 20

typedef __bf16    bf16x8 __attribute__((ext_vector_type(8)));
typedef float     f32x4  __attribute__((ext_vector_type(4)));
typedef _Float16  f16x8  __attribute__((ext_vector_type(8)));

#if __has_builtin(__builtin_amdgcn_exp2f)
#define FEXP2 __builtin_amdgcn_exp2f
#else
#define FEXP2 exp2f
#endif
#if __has_builtin(__builtin_amdgcn_logf)
#define FLOG2 __builtin_amdgcn_logf
#else
#define FLOG2 log2f
#endif

#define LOG2E 1.4426950408889634f
#define LN2F  0.6931471805599453f

// ---------------- kernel 1: normalize vocab -> bf16 table [VOCAB][DP] ----------------
__global__ __launch_bounds__(256) void knorm_embed(const float* __restrict__ emb,
                                                   __hip_bfloat162* __restrict__ tab2) {
    const int v = blockIdx.x;
    const float* row = emb + (size_t)v * DN;
    const int t = threadIdx.x;

    float x0 = (t < DN) ? row[t] : 0.f;
    float x1 = (t + 256 < DN) ? row[t + 256] : 0.f;
    float ss = x0 * x0 + x1 * x1;
    #pragma unroll
    for (int off = 32; off; off >>= 1) ss += __shfl_xor(ss, off);
    __shared__ float red[4];
    if ((t & 63) == 0) red[t >> 6] = ss;
    __syncthreads();
    float tot = red[0] + red[1] + red[2] + red[3];
    float scale = 1.0f / fmaxf(sqrtf(tot), 1e-8f);

    if (t < DP / 2) {
        int e = t * 2;
        float a = (e < DN) ? row[e] * scale : 0.f;
        float b = (e + 1 < DN) ? row[e + 1] * scale : 0.f;
        __hip_bfloat162 p;
        p.x = __float2bfloat16(a);
        p.y = __float2bfloat16(b);
        tab2[(size_t)v * (DP / 2) + t] = p;
    }
}

// ---------------- kernel 2a: GEMM -> sim (f16), at-split two-pass, acc=40 regs ----------------
// Pass a in {0,1}: wave w computes rows {c=w, i = a*16..a*16+15} vs all 10 jg (5 h).
// A-frags loaded DIRECT from global (wave-private rows, pass-constant base, 1-step prefetch).
// B staged to LDS [160][32] ushort per BK=32 slice, single-buffered, reg-staged.
__global__ __launch_bounds__(320, 4) void knrm_gemm(const int* __restrict__ cand,
                                                    const int* __restrict__ clik,
                                                    const ushort* __restrict__ tab,
                                                    _Float16* __restrict__ simg) {
    __shared__ __align__(16) ushort   Bbuf[160 * 32];   // 10 KB
    __shared__ __align__(16) _Float16 simbuf[80 * 32];  // 5 KB (wave-private 16-row bands)
    __shared__ int tokA[160];
    __shared__ int tokB[160];

    const int t    = threadIdx.x;
    const int lane = t & 63;
    const int w    = t >> 6;          // wave 0..4 == candidate c
    // T1: bijective XCD swizzle (grid 1280 = 8 x 160)
    const int bid  = (blockIdx.x & 7) * 160 + (blockIdx.x >> 3);
    const int b    = bid / 10;
    const int hc   = bid % 10;

    if (t < 160) tokA[t] = cand[b * (CN * LN) + t];
    else         tokB[t - 160] = clik[b * (HN * LN) + hc * 160 + (t - 160)];
    __syncthreads();

    const int m15 = lane & 15;
    const int g4  = lane >> 4;

    // B staging: 640 x 16B chunks per slice, 2 per thread; row = chunk>>2, 64B/row/slice
    const int rB0 = t >> 2, c40 = t & 3;
    const int rB1 = 80 + rB0;
    const char* sB0 = (const char*)tab + (size_t)tokB[rB0] * (DP * 2) + c40 * 16;
    const char* sB1 = (const char*)tab + (size_t)tokB[rB1] * (DP * 2) + c40 * 16;
    char* dB0 = (char*)Bbuf + rB0 * 64 + c40 * 16;
    char* dB1 = (char*)Bbuf + rB1 * 64 + c40 * 16;

    const size_t hbase = (size_t)(b * CN) * HN + (size_t)hc * 5;

    #pragma unroll 1
    for (int a = 0; a < 2; ++a) {
        const int rowA = w * 32 + a * 16 + m15;
        const char* sA = (const char*)tab + (size_t)tokA[rowA] * (DP * 2) + g4 * 16;

        f32x4 acc[10];
        #pragma unroll
        for (int jg = 0; jg < 10; ++jg) acc[jg] = (f32x4){0.f, 0.f, 0.f, 0.f};

        // prologue: slice-0 B chunks + A frag
        int4   rgb0 = *(const int4*)sB0;
        int4   rgb1 = *(const int4*)sB1;
        bf16x8 af   = *(const bf16x8*)sA;

        #pragma unroll 1
        for (int ss = 0; ss < 10; ++ss) {
            __syncthreads();                  // Bbuf free (prev compute done)
            *(int4*)dB0 = rgb0;
            *(int4*)dB1 = rgb1;
            __syncthreads();                  // Bbuf ready
            bf16x8 afn = af;
            if (ss < 9) {                     // next-slice loads hide under MFMA phase
                const int ko = (ss + 1) * 64;
                rgb0 = *(const int4*)(sB0 + ko);
                rgb1 = *(const int4*)(sB1 + ko);
                afn  = *(const bf16x8*)(sA + ko);
            }
            #pragma unroll
            for (int jg = 0; jg < 10; ++jg) {
                bf16x8 bf = *(const bf16x8*)((const char*)Bbuf + (jg * 16 + m15) * 64 + g4 * 16);
                acc[jg] = __builtin_amdgcn_mfma_f32_16x16x32_bf16(af, bf, acc[jg], 0, 0, 0);
            }
            af = afn;
        }

        // barrier-free epilogue: simbuf rows [w*16, w*16+16) are wave-private
        // C/D layout col=lane&15, row=(lane>>4)*4+reg [m89-verified]
        #pragma unroll
        for (int hl = 0; hl < 5; ++hl) {
            #pragma unroll
            for (int jgl = 0; jgl < 2; ++jgl)
                #pragma unroll
                for (int r = 0; r < 4; ++r)
                    simbuf[(w * 16 + g4 * 4 + r) * 32 + jgl * 16 + m15] =
                        (_Float16)acc[2 * hl + jgl][r];
            // readback chunk q = t: row = t>>2 in this wave's band; store coalesced int4
            const int c  = t >> 6;            // == w
            const int il = (t >> 2) & 15;
            const int c4 = t & 3;
            int4 v = *(const int4*)((const char*)simbuf + t * 16);
            size_t eoff = ((hbase + (size_t)c * HN + hl) * (LN * LN)
                           + (a * 16 + il) * LN + c4 * 8) * 2;
            *(int4*)((char*)simg + eoff) = v;
        }
    }
}

// ---------------- kernel 2b: streaming kernel-pooling, factorized Gaussians (R5-proven) ----------------
// exp(-50(s-mu_k)^2) = e0 * t^m * e^{-m^2/2},  e0=e^{-50 s^2}, t=e^{10 s}, m=10*mu_k in [-9,9]
__global__ __launch_bounds__(256, 8) void knrm_pool(const _Float16* __restrict__ sim,
                                                    const float* __restrict__ ltr_w,
                                                    float* __restrict__ score) {
    const int n    = blockIdx.x * 256 + threadIdx.x;   // 1,024,000 threads
    const int lane = n & 63;
    const int wv   = n >> 6;          // ((b*C + c)*25 + h2)
    const int bc   = wv / 25;
    const int h2   = wv % 25;
    const int h    = h2 * 2 + (lane >> 5);
    const int i    = lane & 31;

    const f16x8* rowv = (const f16x8*)(sim + ((size_t)(bc * HN + h) * LN + i) * LN);

    const float C1   = 10.0f * LOG2E;    // t  = 2^( C1*s)
    const float C2   = -50.0f * LOG2E;   // e0 = 2^( C2*s^2)
    const float AK19 = 849.3218002880191f;  // sqrt(LOG2E / (2*0.001^2))

    float Q[KNN];
    #pragma unroll
    for (int k = 0; k < KNN; ++k) Q[k] = 0.f;

    #pragma unroll
    for (int jc = 0; jc < 4; ++jc) {
        f16x8 v = rowv[jc];
        #pragma unroll
        for (int e = 0; e < 8; ++e) {
            float s  = (float)v[e];
            float cs = C1 * s;
            float t  = FEXP2(cs);
            float u  = FEXP2(-cs);
            float e0 = FEXP2(C2 * (s * s));
            Q[9] += e0;
            float ap = e0, am = e0;
            ap *= t;  Q[10] += ap;   am *= u;  Q[8] += am;
            ap *= t;  Q[11] += ap;   am *= u;  Q[7] += am;
            ap *= t;  Q[12] += ap;   am *= u;  Q[6] += am;
            ap *= t;  Q[13] += ap;   am *= u;  Q[5] += am;
            ap *= t;  Q[14] += ap;   am *= u;  Q[4] += am;
            ap *= t;  Q[15] += ap;   am *= u;  Q[3] += am;
            ap *= t;  Q[16] += ap;   am *= u;  Q[2] += am;
            ap *= t;  Q[17] += ap;   am *= u;  Q[1] += am;
            ap *= t;  Q[18] += ap;   am *= u;  Q[0] += am;
            float d = fmaf(s, AK19, -AK19);          // (s-1)*AK19
            Q[19] += FEXP2(-(d * d));                // sharp sigma=0.001 kernel
        }
    }

    // e^{-m^2/2} for |m|=0..9
    static const float CkT[10] = {
        1.0f, 0.6065306597126334f, 0.1353352832366127f, 0.011108996538242306f,
        3.3546262790251185e-4f, 3.7266531720786709e-6f, 1.5229979744712628e-8f,
        2.2897348456191135e-11f, 1.2664165549094176e-14f, 2.576757109154981e-18f };

    const float* wrow = ltr_w + h * KNN;
    float res = 0.f;
    #pragma unroll
    for (int k = 0; k < KNN - 1; ++k) {
        int a = (k < 9) ? (9 - k) : (k - 9);
        float p = fmaxf(Q[k] * CkT[a], 1e-10f);
        res += wrow[k] * FLOG2(p);
    }
    res += wrow[KNN - 1] * FLOG2(fmaxf(Q[KNN - 1], 1e-10f));
    res *= LN2F;

    #pragma unroll
    for (int off = 32; off; off >>= 1) res += __shfl_xor(res, off);
    if (lane == 0) atomicAdd(&score[bc], res);
}

// Slice buffers: [row][64 ushorts] = 128B rows; 16B chunks XOR-swizzled (fallback only).
__device__ inline bf16x8 ldfrag(const ushort* buf, int row, int chunk) {
    int pos = chunk ^ (row & 7);
    return *(const bf16x8*)((const char*)buf + row * 128 + pos * 16);
}

// ---------------- fallback fused kernel (R3-proven) for small ws ----------------
__global__ __launch_bounds__(320, 4) void knrm_fused(const int* __restrict__ cand,
                                                     const int* __restrict__ clik,
                                                     const ushort* __restrict__ tab,
                                                     const float* __restrict__ ltr_w,
                                                     float* __restrict__ score) {
    __shared__ __align__(16) ushort   Abuf[160 * 64];
    __shared__ __align__(16) ushort   Bbuf[160 * 64];
    __shared__ __align__(16) _Float16 simbuf[160 * 32];
    __shared__ int   tokA[160];
    __shared__ int   tokB[160];
    __shared__ float red[5][5];

    const int t    = threadIdx.x;
    const int lane = t & 63;
    const int w    = t >> 6;
    const int bid  = blockIdx.x;
    const int b    = bid / 10;
    const int hc   = bid % 10;

    if (t < 160) tokA[t] = cand[b * (CN * LN) + t];
    else         tokB[t - 160] = clik[b * (HN * LN) + hc * 160 + (t - 160)];
    __syncthreads();

    const int m15 = lane & 15;
    const int g4  = lane >> 4;

    f32x4 acc[2][10];
    #pragma unroll
    for (int at = 0; at < 2; ++at)
        #pragma unroll
        for (int jg = 0; jg < 10; ++jg)
            acc[at][jg] = (f32x4){0.f, 0.f, 0.f, 0.f};

    for (int ss = 0; ss < 5; ++ss) {
        __syncthreads();
        {
            int4 rg[4];
            #pragma unroll
            for (int it = 0; it < 4; ++it) {
                int cid = it * 320 + t, row = cid >> 3, c = cid & 7;
                rg[it] = *(const int4*)((const char*)tab +
                    (size_t)tokA[row] * (DP * 2) + ss * 128 + ((c ^ (row & 7)) << 4));
            }
            #pragma unroll
            for (int it = 0; it < 4; ++it) {
                int cid = it * 320 + t, row = cid >> 3, c = cid & 7;
                *(int4*)((char*)Abuf + row * 128 + c * 16) = rg[it];
            }
            #pragma unroll
            for (int it = 0; it < 4; ++it) {
                int cid = it * 320 + t, row = cid >> 3, c = cid & 7;
                rg[it] = *(const int4*)((const char*)tab +
                    (size_t)tokB[row] * (DP * 2) + ss * 128 + ((c ^ (row & 7)) << 4));
            }
            #pragma unroll
            for (int it = 0; it < 4; ++it) {
                int cid = it * 320 + t, row = cid >> 3, c = cid & 7;
                *(int4*)((char*)Bbuf + row * 128 + c * 16) = rg[it];
            }
        }
        __syncthreads();
        #pragma unroll
        for (int kc = 0; kc < 2; ++kc) {
            bf16x8 af0 = ldfrag(Abuf, w * 32 + m15,      kc * 4 + g4);
            bf16x8 af1 = ldfrag(Abuf, w * 32 + 16 + m15, kc * 4 + g4);
            #pragma unroll
            for (int jg = 0; jg < 10; ++jg) {
                bf16x8 bf = ldfrag(Bbuf, jg * 16 + m15, kc * 4 + g4);
                acc[0][jg] = __builtin_amdgcn_mfma_f32_16x16x32_bf16(af0, bf, acc[0][jg], 0, 0, 0);
                acc[1][jg] = __builtin_amdgcn_mfma_f32_16x16x32_bf16(af1, bf, acc[1][jg], 0, 0, 0);
            }
        }
    }

    const int kq = t % 20;
    const int r0 = t / 20;
    const float sig = (kq == 19) ? 0.001f : 0.1f;
    const float ak  = sqrtf(LOG2E / (2.0f * sig * sig));
    const float bk  = -(0.1f * (float)kq - 0.9f) * ak;

    float accs[5] = {0.f, 0.f, 0.f, 0.f, 0.f};

    #pragma unroll
    for (int h = 0; h < 5; ++h) {
        __syncthreads();
        #pragma unroll
        for (int at = 0; at < 2; ++at)
            #pragma unroll
            for (int jgl = 0; jgl < 2; ++jgl)
                #pragma unroll
                for (int r = 0; r < 4; ++r) {
                    int i = w * 32 + at * 16 + g4 * 4 + r;
                    int j = jgl * 16 + m15;
                    simbuf[i * 32 + j] = (_Float16)acc[at][2 * h + jgl][r];
                }
        __syncthreads();

        const float wl = ltr_w[(hc * 5 + h) * KNN + kq] * LN2F;
        #pragma unroll
        for (int it = 0; it < 10; ++it) {
            const f16x8* srow = (const f16x8*)&simbuf[(it * 16 + r0) * 32];
            float p0 = 0.f, p1 = 0.f, p2 = 0.f, p3 = 0.f;
            #pragma unroll
            for (int jc = 0; jc < 4; ++jc) {
                f16x8 v = srow[jc];
                float d0 = fmaf((float)v[0], ak, bk);
                float d1 = fmaf((float)v[1], ak, bk);
                float d2 = fmaf((float)v[2], ak, bk);
                float d3 = fmaf((float)v[3], ak, bk);
                float d4 = fmaf((float)v[4], ak, bk);
                float d5 = fmaf((float)v[5], ak, bk);
                float d6 = fmaf((float)v[6], ak, bk);
                float d7 = fmaf((float)v[7], ak, bk);
                p0 += FEXP2(-(d0 * d0));
                p1 += FEXP2(-(d1 * d1));
                p2 += FEXP2(-(d2 * d2));
                p3 += FEXP2(-(d3 * d3));
                p0 += FEXP2(-(d4 * d4));
                p1 += FEXP2(-(d5 * d5));
                p2 += FEXP2(-(d6 * d6));
                p3 += FEXP2(-(d7 * d7));
            }
            float pooled = fmaxf((p0 + p1) + (p2 + p3), 1e-10f);
            accs[it >> 1] += FLOG2(pooled) * wl;
        }
    }

    #pragma unroll
    for (int c = 0; c < 5; ++c) {
        float v = accs[c];
        #pragma unroll
        for (int off = 32; off; off >>= 1) v += __shfl_xor(v, off);
        accs[c] = v;
    }
    __syncthreads();
    if (lane == 0)
        #pragma unroll
        for (int c = 0; c < 5; ++c) red[w][c] = accs[c];
    __syncthreads();
    if (t < 5) {
        float s = red[0][t] + red[1][t] + red[2][t] + red[3][t] + red[4][t];
        atomicAdd(&score[b * CN + t], s);
    }
}

// ---------------- kernel 3: log_softmax over C (ltr_b cancels) ----------------
__global__ __launch_bounds__(128) void knrm_final(const float* __restrict__ score,
                                                  float* __restrict__ out) {
    int b = threadIdx.x;
    if (b < BN) {
        float s[CN];
        float m = -1e30f;
        #pragma unroll
        for (int c = 0; c < CN; ++c) { s[c] = score[b * CN + c]; m = fmaxf(m, s[c]); }
        float sum = 0.f;
        #pragma unroll
        for (int c = 0; c < CN; ++c) sum += FEXP2((s[c] - m) * LOG2E);
        float lse = m + FLOG2(sum) * LN2F;
        #pragma unroll
        for (int c = 0; c < CN; ++c) out[b * CN + c] = s[c] - lse;
    }
}

extern "C" void kernel_launch(void* const* d_in, const int* in_sizes, int n_in,
                              void* d_out, int out_size, void* d_ws, size_t ws_size,
                              hipStream_t stream) {
    const int*   cand  = (const int*)d_in[0];   // [B,C,L]
    const int*   clik  = (const int*)d_in[1];   // [B,H,L]
    const float* emb   = (const float*)d_in[2]; // [VOCAB,D]
    const float* ltr_w = (const float*)d_in[3]; // [1,H*KN]
    float* out = (float*)d_out;

    const size_t TAB_B = (size_t)VOCABN * DP * 2;                 // 32,000,000
    const size_t SIM_B = (size_t)BN * CN * HN * LN * LN * 2;      // 65,536,000

    __hip_bfloat162* tab2 = (__hip_bfloat162*)d_ws;
    ushort* tab = (ushort*)d_ws;

    knorm_embed<<<VOCABN, 256, 0, stream>>>(emb, tab2);

    if (ws_size >= TAB_B + SIM_B + BN * CN * sizeof(float)) {
        _Float16* simg = (_Float16*)((char*)d_ws + TAB_B);
        float* score   = (float*)((char*)d_ws + TAB_B + SIM_B);
        hipMemsetAsync(score, 0, BN * CN * sizeof(float), stream);
        knrm_gemm<<<BN * 10, 320, 0, stream>>>(cand, clik, tab, simg);
        knrm_pool<<<(BN * CN * HN * LN) / 256, 256, 0, stream>>>(simg, ltr_w, score);
        knrm_final<<<1, 128, 0, stream>>>(score, out);
    } else {
        float* score = (float*)((char*)d_ws + TAB_B);
        hipMemsetAsync(score, 0, BN * CN * sizeof(float), stream);
        knrm_fused<<<BN * 10, 320, 0, stream>>>(cand, clik, tab, ltr_w, score);
        knrm_final<<<1, 128, 0, stream>>>(score, out);
    }
}